// Round 1
// baseline (287.581 us; speedup 1.0000x reference)
//
#include <hip/hip_runtime.h>

#define B_DIM 4096
#define K_TOT 2048   // IN + H
#define H_DIM 1024

typedef short bf16x8 __attribute__((ext_vector_type(8)));
typedef float f32x4 __attribute__((ext_vector_type(4)));
typedef unsigned short u16x8 __attribute__((ext_vector_type(8)));

typedef __attribute__((address_space(1))) const unsigned gas_u32;
typedef __attribute__((address_space(3))) unsigned las_u32;

static __device__ __forceinline__ unsigned short f2bf(float f) {
  union { float f; unsigned u; } v; v.f = f;
  unsigned r = v.u + 0x7FFF + ((v.u >> 16) & 1);  // RNE
  return (unsigned short)(r >> 16);
}

// ---------------- merged pack: A = [x | h] (B x 2048) and W (4096 x 2048), bf16 ----------------
// One launch instead of two; boundary (t == 2^20) is block-aligned so the branch is
// wave-uniform everywhere.
__global__ void pack_all(const float* __restrict__ x, const float* __restrict__ hp,
                         const float* __restrict__ W0, const float* __restrict__ W1,
                         const float* __restrict__ W2, const float* __restrict__ W3,
                         const float* __restrict__ W4, const float* __restrict__ W5,
                         const float* __restrict__ W6, const float* __restrict__ W7,
                         u16x8* __restrict__ A, u16x8* __restrict__ Wc) {
  const int t = blockIdx.x * blockDim.x + threadIdx.x;
  const int NA = (B_DIM * K_TOT) >> 3;   // 1048576 threads for A
  const float* src;
  u16x8* dst;
  if (t < NA) {
    int idx = t << 3;
    int b = idx >> 11;
    int k = idx & 2047;
    src = (k < 1024) ? (x + b * 1024 + k) : (hp + b * 1024 + (k - 1024));
    dst = A + t;
  } else {
    int u = t - NA;
    int idx = u << 3;
    int n = idx >> 11;                // output row (gate*1024 + j)
    int k = idx & 2047;
    int gate = n >> 10;
    int j = n & 1023;
    int s = (k < 1024) ? gate : gate + 4;   // 0..3 -> Wx gates, 4..7 -> Wh gates
    const float* base =
        (s == 0) ? W0 : (s == 1) ? W1 : (s == 2) ? W2 : (s == 3) ? W3 :
        (s == 4) ? W4 : (s == 5) ? W5 : (s == 6) ? W6 : W7;
    src = base + j * 1024 + (k & 1023);
    dst = Wc + u;
  }
  float4 lo = *(const float4*)src;
  float4 hi = *(const float4*)(src + 4);
  u16x8 v;
  v[0] = f2bf(lo.x); v[1] = f2bf(lo.y); v[2] = f2bf(lo.z); v[3] = f2bf(lo.w);
  v[4] = f2bf(hi.x); v[5] = f2bf(hi.y); v[6] = f2bf(hi.z); v[7] = f2bf(hi.w);
  *dst = v;
}

// ------------- fused GEMM + LSTM epilogue, double-buffered LDS (2-phase) -------------
// Block: 128 rows x (4 gates x 32 j-cols). Wave: 64 rows x (4 gates x 16 j).
// acc[mi][gate] -> each lane holds z_i,z_f,z_g,z_o for the SAME (row,j), so the
// LSTM pointwise is in-register.
// LDS slot swizzle: 16B slot s at row r holds global k-group g = s ^ ((r>>1)&3)
// -> ds_read_b128 conflicts drop from 8-way to 2-way (free).
// Pipeline: STAGE(buf^1, k0+32) issued BEFORE ds_read/MFMA of buf; single
// __syncthreads() per K-step (its vmcnt(0)+lgkmcnt(0) drain is the exact wait
// we need). Global-load latency hides under the 16 MFMAs instead of ahead of them.
static __device__ __forceinline__ float sigm(float x) {
  return 1.0f / (1.0f + __expf(-x));
}
static __device__ __forceinline__ float tanh_fast(float x) {
  x = fminf(fmaxf(x, -15.f), 15.f);
  float t = __expf(-2.0f * x);
  return (1.0f - t) / (1.0f + t);
}

__global__ __launch_bounds__(256) void gemm_lstm(
    const unsigned short* __restrict__ A,   // B x 2048 bf16
    const unsigned short* __restrict__ W,   // 4096 x 2048 bf16, gate-major rows
    const float* __restrict__ cp,
    const float* __restrict__ bii, const float* __restrict__ bif,
    const float* __restrict__ big, const float* __restrict__ bio,
    float* __restrict__ out) {
  __shared__ unsigned short As[2][128 * 32];
  __shared__ unsigned short Bs[2][128 * 32];
  const int tid = threadIdx.x;
  const int wave = tid >> 6;
  const int lane = tid & 63;
  const int m0 = blockIdx.y << 7;       // 128-row strip
  const int j0 = blockIdx.x << 5;       // 32-wide j strip
  const int wm = (wave >> 1) << 6;      // wave row half (64)
  const int wj16 = (wave & 1) << 4;     // wave j half (16)

  f32x4 acc[4][4];
#pragma unroll
  for (int mi = 0; mi < 4; ++mi)
#pragma unroll
    for (int ni = 0; ni < 4; ++ni)
      acc[mi][ni] = (f32x4){0.f, 0.f, 0.f, 0.f};

  // ---- staging geometry: wave stages chunks c0,c0+1 for A and B (16 rows x 64B each)
  const int c0 = wave * 2;
  const int lr = lane >> 2;                       // row within chunk
  const int ls = lane & 3;                        // LDS 16B slot
  const int g  = ls ^ ((lr >> 1) & 3);            // swizzled global k-group
  const unsigned short* aptr0 = A + (long)(m0 + c0 * 16 + lr) * K_TOT + g * 8;
  const unsigned short* aptr1 = aptr0 + 16 * K_TOT;
  const int rr0 = c0 * 16 + lr;                   // LDS B row (gate-interleaved)
  const int rr1 = rr0 + 16;
  const unsigned short* bptr0 =
      W + (long)((rr0 >> 5) * 1024 + j0 + (rr0 & 31)) * K_TOT + g * 8;
  const unsigned short* bptr1 =
      W + (long)((rr1 >> 5) * 1024 + j0 + (rr1 & 31)) * K_TOT + g * 8;
  const int stg_off = c0 * 1024;                  // byte offset of wave's chunk pair

#define STAGE(buf, kk)                                                                   \
  do {                                                                                   \
    char* la = (char*)As + (buf) * 8192 + stg_off;                                       \
    char* lb = (char*)Bs + (buf) * 8192 + stg_off;                                       \
    __builtin_amdgcn_global_load_lds((gas_u32*)(aptr0 + (kk)), (las_u32*)la, 16, 0, 0);  \
    __builtin_amdgcn_global_load_lds((gas_u32*)(aptr1 + (kk)), (las_u32*)(la + 1024), 16, 0, 0); \
    __builtin_amdgcn_global_load_lds((gas_u32*)(bptr0 + (kk)), (las_u32*)lb, 16, 0, 0);  \
    __builtin_amdgcn_global_load_lds((gas_u32*)(bptr1 + (kk)), (las_u32*)(lb + 1024), 16, 0, 0); \
  } while (0)

  const int fr = lane & 15;                       // fragment row within 16-tile
  const int gg = lane >> 4;                       // k-group 0..3
  const int sl = (gg ^ ((fr >> 1) & 3)) * 16;     // swizzled slot byte offset

  // prologue: fill buffer 0
  STAGE(0, 0);
  __syncthreads();

  int cur = 0;
  for (int k0 = 0; k0 < K_TOT; k0 += 32) {
    if (k0 + 32 < K_TOT) STAGE(cur ^ 1, k0 + 32);   // prefetch next tile (in flight under MFMA)
    const char* baseA = (const char*)As + cur * 8192;
    const char* baseB = (const char*)Bs + cur * 8192;
    bf16x8 af[4], bfv[4];
#pragma unroll
    for (int i = 0; i < 4; ++i) {
      af[i]  = *(const bf16x8*)(baseA + (wm + i * 16 + fr) * 64 + sl);
      bfv[i] = *(const bf16x8*)(baseB + (i * 32 + wj16 + fr) * 64 + sl);
    }
#pragma unroll
    for (int mi = 0; mi < 4; ++mi)
#pragma unroll
      for (int ni = 0; ni < 4; ++ni)
        acc[mi][ni] = __builtin_amdgcn_mfma_f32_16x16x32_bf16(af[mi], bfv[ni], acc[mi][ni], 0, 0, 0);
    __syncthreads();   // drains vmcnt(0)+lgkmcnt(0): next buffer staged, this one free
    cur ^= 1;
  }
#undef STAGE

  // ---- fused LSTM epilogue
  // C/D layout: col=lane&15, row=(lane>>4)*4+reg  [m89/m91 verified]
  const int ccol = lane & 15;
  const int crow = (lane >> 4) * 4;
  const int j = j0 + wj16 + ccol;
  const float bi = bii[j];
  const float bff = bif[j];
  const float bg = big[j];
  const float bo = bio[j];
  const long BH = (long)B_DIM * H_DIM;
#pragma unroll
  for (int mi = 0; mi < 4; ++mi) {
#pragma unroll
    for (int reg = 0; reg < 4; ++reg) {
      const int row = m0 + wm + mi * 16 + crow + reg;
      const long p = (long)row * H_DIM + j;
      const float cvp = cp[p];
      const float iv = sigm(acc[mi][0][reg] + bi);
      const float fv = sigm(acc[mi][1][reg] + bff);
      const float gv = tanh_fast(acc[mi][2][reg] + bg);
      const float ov = sigm(acc[mi][3][reg] + bo);
      const float cv = fv * cvp + iv * gv;
      const float hv = ov * tanh_fast(cv);
      // streamed once, never re-read -> nontemporal to keep L2 for A/W panels
      __builtin_nontemporal_store(hv, &out[p]);
      __builtin_nontemporal_store(cv, &out[BH + p]);
      __builtin_nontemporal_store(iv, &out[2 * BH + p]);
      __builtin_nontemporal_store(fv, &out[3 * BH + p]);
      __builtin_nontemporal_store(gv, &out[4 * BH + p]);
      __builtin_nontemporal_store(ov, &out[5 * BH + p]);
    }
  }
}

extern "C" void kernel_launch(void* const* d_in, const int* in_sizes, int n_in,
                              void* d_out, int out_size, void* d_ws, size_t ws_size,
                              hipStream_t stream) {
  const float* x    = (const float*)d_in[0];
  const float* h    = (const float*)d_in[1];
  const float* c    = (const float*)d_in[2];
  const float* W_ii = (const float*)d_in[3];
  const float* b_ii = (const float*)d_in[4];
  const float* W_if = (const float*)d_in[5];
  const float* b_if = (const float*)d_in[6];
  const float* W_ig = (const float*)d_in[7];
  const float* b_ig = (const float*)d_in[8];
  const float* W_io = (const float*)d_in[9];
  const float* b_io = (const float*)d_in[10];
  const float* W_hi = (const float*)d_in[11];
  const float* W_hf = (const float*)d_in[12];
  const float* W_hg = (const float*)d_in[13];
  const float* W_ho = (const float*)d_in[14];

  // workspace: A_cat bf16 16MB | W_cat bf16 16MB
  unsigned short* Abf = (unsigned short*)d_ws;
  unsigned short* Wbf = (unsigned short*)((char*)d_ws + (size_t)16 * 1024 * 1024);

  // one pack launch: 2*2^20 threads (A first half, W second half)
  pack_all<<<8192, 256, 0, stream>>>(x, h, W_ii, W_if, W_ig, W_io,
                                     W_hi, W_hf, W_hg, W_ho,
                                     (u16x8*)Abf, (u16x8*)Wbf);
  dim3 grid(H_DIM / 32, B_DIM / 128);   // 32 x 32 blocks
  gemm_lstm<<<grid, 256, 0, stream>>>(Abf, Wbf, c, b_ii, b_if, b_ig, b_io,
                                      (float*)d_out);
}

// Round 2
// 259.602 us; speedup vs baseline: 1.1078x; 1.1078x over previous
//
#include <hip/hip_runtime.h>

#define B_DIM 4096
#define K_TOT 2048   // IN + H
#define H_DIM 1024

typedef short bf16x8 __attribute__((ext_vector_type(8)));
typedef float f32x4 __attribute__((ext_vector_type(4)));
typedef unsigned short u16x8 __attribute__((ext_vector_type(8)));

typedef __attribute__((address_space(1))) const unsigned gas_u32;
typedef __attribute__((address_space(3))) unsigned las_u32;

static __device__ __forceinline__ unsigned short f2bf(float f) {
  union { float f; unsigned u; } v; v.f = f;
  unsigned r = v.u + 0x7FFF + ((v.u >> 16) & 1);  // RNE
  return (unsigned short)(r >> 16);
}

// ---------------- merged pack: A = [x | h] (B x 2048) and W (4096 x 2048) bf16 ----------------
// W packed row R encodes (bx, ng, gate, c):  R = bx*256 + gate*64 + ... NO:
//   u = R & 255;  gate = (u>>4)&3;  ng = u>>6;  c = u&15;  j = (R>>8)*64 + ng*16 + c
// This makes MFMA B-fragment ni == gate while wave ng owns a contiguous 16-j strip,
// so the LSTM pointwise has all 4 gates of (row,j) in one lane's accumulators.
__global__ void pack_all(const float* __restrict__ x, const float* __restrict__ hp,
                         const float* __restrict__ W0, const float* __restrict__ W1,
                         const float* __restrict__ W2, const float* __restrict__ W3,
                         const float* __restrict__ W4, const float* __restrict__ W5,
                         const float* __restrict__ W6, const float* __restrict__ W7,
                         u16x8* __restrict__ A, u16x8* __restrict__ Wc) {
  const int t = blockIdx.x * blockDim.x + threadIdx.x;
  const int NA = (B_DIM * K_TOT) >> 3;   // 1048576 threads for A
  const float* src;
  u16x8* dst;
  if (t < NA) {
    int idx = t << 3;
    int b = idx >> 11;
    int k = idx & 2047;
    src = (k < 1024) ? (x + b * 1024 + k) : (hp + b * 1024 + (k - 1024));
    dst = A + t;
  } else {
    int u_ = t - NA;
    int idx = u_ << 3;
    int R = idx >> 11;                 // packed W row 0..4095
    int k = idx & 2047;
    int uu = R & 255;
    int gate = (uu >> 4) & 3;
    int ngg = uu >> 6;
    int cc = uu & 15;
    int j = (R >> 8) * 64 + ngg * 16 + cc;
    int s = (k < 1024) ? gate : gate + 4;   // x-half -> Wx gate, h-half -> Wh gate
    const float* base =
        (s == 0) ? W0 : (s == 1) ? W1 : (s == 2) ? W2 : (s == 3) ? W3 :
        (s == 4) ? W4 : (s == 5) ? W5 : (s == 6) ? W6 : W7;
    src = base + j * 1024 + (k & 1023);
    dst = Wc + u_;
  }
  float4 lo = *(const float4*)src;
  float4 hi = *(const float4*)(src + 4);
  u16x8 v;
  v[0] = f2bf(lo.x); v[1] = f2bf(lo.y); v[2] = f2bf(lo.z); v[3] = f2bf(lo.w);
  v[4] = f2bf(hi.x); v[5] = f2bf(hi.y); v[6] = f2bf(hi.z); v[7] = f2bf(hi.w);
  *dst = v;
}

static __device__ __forceinline__ float sigm(float x) {
  return 1.0f / (1.0f + __expf(-x));
}
static __device__ __forceinline__ float tanh_fast(float x) {
  x = fminf(fmaxf(x, -15.f), 15.f);
  float t = __expf(-2.0f * x);
  return (1.0f - t) / (1.0f + t);
}

// ------------- 256x256 8-phase counted-vmcnt GEMM + fused LSTM epilogue -------------
// BM=BN=256, BK=64. 8 waves = 2(M) x 4(N). Per-wave 128 rows x 64 cols = acc[8][4].
// LDS: 2 buffers x (A 32KB + B 32KB) = 128KB, each matrix [kh][256 rows][4 slots x 16B],
// slot swizzle pslot = g ^ ((row>>1)&3) (staged via pre-swizzled GLOBAL source, linear
// LDS dest as global_load_lds requires; read with the same involution -> dense 1KB
// span per ds_read_b128 wave = conflict-free).
// Half-tile stream H=0..127 (tile kt = H>>2; H&1: A/B; (H>>1)&1: k-half). Stage runs
// D=6 halves ahead; guards s_waitcnt vmcnt(8) at the two k-half boundaries per tile
// (exact: in-flight = 4 halves x 2 loads). Tail peeled: tile 30 p3 -> vmcnt(4),
// tile 31 p1 -> vmcnt(0). Raw s_barrier (x2/phase) keeps prefetch alive across
// barriers; setprio(1) wraps the MFMA cluster (T5 pays only in phase-split regime).
__global__ __launch_bounds__(512, 2) void gemm_lstm(
    const unsigned short* __restrict__ A,   // B x 2048 bf16
    const unsigned short* __restrict__ W,   // 4096 x 2048 bf16, packed per above
    const float* __restrict__ cp,
    const float* __restrict__ bii, const float* __restrict__ bif,
    const float* __restrict__ big, const float* __restrict__ bio,
    float* __restrict__ out) {
  extern __shared__ char lds[];   // 131072 B
  const int tid = threadIdx.x;
  const int w = tid >> 6;
  const int lane = tid & 63;
  const int wm = w >> 2;          // 0..1 : M half
  const int ng = w & 3;           // 0..3 : N quarter
  const int bx = blockIdx.x;      // 64-wide j strip
  const int by = blockIdx.y;      // 256-row strip

  f32x4 acc[8][4];
#pragma unroll
  for (int i = 0; i < 8; ++i)
#pragma unroll
    for (int n = 0; n < 4; ++n)
      acc[i][n] = (f32x4){0.f, 0.f, 0.f, 0.f};

  // ---- staging constants: thread covers linear LDS slots v0, v1 of each 16KB half
  const int v0 = tid, v1 = tid + 512;
  const int r0 = v0 >> 2, g0 = (v0 & 3) ^ ((r0 >> 1) & 3);
  const int r1 = v1 >> 2, g1 = (v1 & 3) ^ ((r1 >> 1) & 3);
  const unsigned short* srcA0 = A + (long)(by * 256 + r0) * K_TOT + g0 * 8;
  const unsigned short* srcA1 = A + (long)(by * 256 + r1) * K_TOT + g1 * 8;
  const unsigned short* srcB0 = W + (long)(bx * 256 + r0) * K_TOT + g0 * 8;
  const unsigned short* srcB1 = W + (long)(bx * 256 + r1) * K_TOT + g1 * 8;
  const int d0 = v0 << 4, d1 = v1 << 4;

  // ---- fragment-read constants
  const int fr = lane & 15;
  const int gg = lane >> 4;
  const int aoff = fr * 64 + ((gg ^ ((fr >> 1) & 3)) << 4);
  const int wmoff = wm << 13;     // wm*128 rows * 64B
  const int ngoff = ng << 12;     // ng*64 rows * 64B

  bf16x8 bfr[4];

#define STAGE(H)                                                               \
  {                                                                            \
    const int H_ = (H);                                                        \
    const int koff_ = (H_ >> 1) * 32;                                          \
    char* dst_ = lds + (((H_ >> 2) & 1) << 16) + ((H_ & 1) << 15) +            \
                 (((H_ >> 1) & 1) << 14);                                      \
    if (H_ & 1) {                                                              \
      __builtin_amdgcn_global_load_lds((gas_u32*)(srcB0 + koff_),              \
                                       (las_u32*)(dst_ + d0), 16, 0, 0);       \
      __builtin_amdgcn_global_load_lds((gas_u32*)(srcB1 + koff_),              \
                                       (las_u32*)(dst_ + d1), 16, 0, 0);       \
    } else {                                                                   \
      __builtin_amdgcn_global_load_lds((gas_u32*)(srcA0 + koff_),              \
                                       (las_u32*)(dst_ + d0), 16, 0, 0);       \
      __builtin_amdgcn_global_load_lds((gas_u32*)(srcA1 + koff_),              \
                                       (las_u32*)(dst_ + d1), 16, 0, 0);       \
    }                                                                          \
  }

#define G8 asm volatile("s_waitcnt vmcnt(8)" ::: "memory")
#define G4 asm volatile("s_waitcnt vmcnt(4)" ::: "memory")
#define G0 asm volatile("s_waitcnt vmcnt(0)" ::: "memory")
#define GN ((void)0)

#define DO_PHASE(P, KT, GUARD, DOSTAGE)                                        \
  {                                                                            \
    const char* lA_ = ldsbuf + ((P) >> 1) * 16384;                             \
    const char* lB_ = ldsbuf + 32768 + ((P) >> 1) * 16384;                     \
    bf16x8 af_[4];                                                             \
    _Pragma("unroll")                                                          \
    for (int i_ = 0; i_ < 4; ++i_)                                             \
      af_[i_] = *(const bf16x8*)(lA_ + wmoff + (((P) & 1) * 4 + i_) * 1024 + aoff); \
    if (((P) & 1) == 0) {                                                      \
      _Pragma("unroll")                                                        \
      for (int n_ = 0; n_ < 4; ++n_)                                           \
        bfr[n_] = *(const bf16x8*)(lB_ + ngoff + n_ * 1024 + aoff);            \
    }                                                                          \
    if (DOSTAGE) STAGE((KT) * 4 + (P) + 6);                                    \
    GUARD;                                                                     \
    __builtin_amdgcn_s_barrier();                                              \
    asm volatile("s_waitcnt lgkmcnt(0)" ::: "memory");                         \
    __builtin_amdgcn_sched_barrier(0);                                         \
    __builtin_amdgcn_s_setprio(1);                                             \
    _Pragma("unroll")                                                          \
    for (int i_ = 0; i_ < 4; ++i_) {                                           \
      _Pragma("unroll")                                                        \
      for (int n_ = 0; n_ < 4; ++n_)                                           \
        acc[((P) & 1) * 4 + i_][n_] = __builtin_amdgcn_mfma_f32_16x16x32_bf16( \
            af_[i_], bfr[n_], acc[((P) & 1) * 4 + i_][n_], 0, 0, 0);           \
    }                                                                          \
    __builtin_amdgcn_s_setprio(0);                                             \
    __builtin_amdgcn_s_barrier();                                              \
  }

  // ---- prologue: stage halves 0..5, wait for halves 0,1 (4 in flight = 8 loads)
  STAGE(0); STAGE(1); STAGE(2); STAGE(3); STAGE(4); STAGE(5);
  asm volatile("s_waitcnt vmcnt(8)" ::: "memory");
  __builtin_amdgcn_s_barrier();

  // ---- main loop: tiles 0..29, steady-state vmcnt(8)
  for (int kt = 0; kt < 30; ++kt) {
    const char* ldsbuf = lds + ((kt & 1) << 16);
    DO_PHASE(0, kt, GN, 1);
    DO_PHASE(1, kt, G8, 1);
    DO_PHASE(2, kt, GN, 1);
    DO_PHASE(3, kt, G8, 1);
  }
  // tile 30 (buffer 0): stages halves 126,127 then stream ends
  {
    const char* ldsbuf = lds;
    DO_PHASE(0, 30, GN, 1);
    DO_PHASE(1, 30, G8, 1);
    DO_PHASE(2, 30, GN, 0);
    DO_PHASE(3, 30, G4, 0);
  }
  // tile 31 (buffer 1): drain
  {
    const char* ldsbuf = lds + 65536;
    DO_PHASE(0, 31, GN, 0);
    DO_PHASE(1, 31, G0, 0);
    DO_PHASE(2, 31, GN, 0);
    DO_PHASE(3, 31, GN, 0);
  }
#undef DO_PHASE
#undef STAGE

  // ---- fused LSTM epilogue
  // C/D layout: col=lane&15, row=(lane>>4)*4+reg  [m89/m91 verified]
  // frag ni == gate; j = bx*64 + ng*16 + ccol
  const int ccol = lane & 15;
  const int crow = (lane >> 4) << 2;
  const int j = (bx << 6) + (ng << 4) + ccol;
  const float bi = bii[j];
  const float bff = bif[j];
  const float bg = big[j];
  const float bo = bio[j];
  const long BH = (long)B_DIM * H_DIM;
  const int row0 = (by << 8) + (wm << 7) + crow;
#pragma unroll
  for (int mi = 0; mi < 8; ++mi) {
#pragma unroll
    for (int reg = 0; reg < 4; ++reg) {
      const int row = row0 + mi * 16 + reg;
      const long p = (long)row * H_DIM + j;
      const float cvp = cp[p];
      const float iv = sigm(acc[mi][0][reg] + bi);
      const float fv = sigm(acc[mi][1][reg] + bff);
      const float gv = tanh_fast(acc[mi][2][reg] + bg);
      const float ov = sigm(acc[mi][3][reg] + bo);
      const float cv = fv * cvp + iv * gv;
      const float hv = ov * tanh_fast(cv);
      out[p]          = hv;
      out[BH + p]     = cv;
      out[2 * BH + p] = iv;
      out[3 * BH + p] = fv;
      out[4 * BH + p] = gv;
      out[5 * BH + p] = ov;
    }
  }
}

extern "C" void kernel_launch(void* const* d_in, const int* in_sizes, int n_in,
                              void* d_out, int out_size, void* d_ws, size_t ws_size,
                              hipStream_t stream) {
  const float* x    = (const float*)d_in[0];
  const float* h    = (const float*)d_in[1];
  const float* c    = (const float*)d_in[2];
  const float* W_ii = (const float*)d_in[3];
  const float* b_ii = (const float*)d_in[4];
  const float* W_if = (const float*)d_in[5];
  const float* b_if = (const float*)d_in[6];
  const float* W_ig = (const float*)d_in[7];
  const float* b_ig = (const float*)d_in[8];
  const float* W_io = (const float*)d_in[9];
  const float* b_io = (const float*)d_in[10];
  const float* W_hi = (const float*)d_in[11];
  const float* W_hf = (const float*)d_in[12];
  const float* W_hg = (const float*)d_in[13];
  const float* W_ho = (const float*)d_in[14];

  // workspace: A_cat bf16 16MB | W_cat bf16 16MB
  unsigned short* Abf = (unsigned short*)d_ws;
  unsigned short* Wbf = (unsigned short*)((char*)d_ws + (size_t)16 * 1024 * 1024);

  static bool s_attr = false;
  if (!s_attr) {
    hipFuncSetAttribute((const void*)gemm_lstm,
                        hipFuncAttributeMaxDynamicSharedMemorySize, 131072);
    s_attr = true;
  }

  pack_all<<<8192, 256, 0, stream>>>(x, h, W_ii, W_if, W_ig, W_io,
                                     W_hi, W_hf, W_hg, W_ho,
                                     (u16x8*)Abf, (u16x8*)Wbf);
  dim3 grid(H_DIM / 64, B_DIM / 256);   // 16 x 16 = 256 blocks = 1/CU
  gemm_lstm<<<grid, 512, 131072, stream>>>(Abf, Wbf, c, b_ii, b_if, b_ig, b_io,
                                           (float*)d_out);
}

// Round 4
// 256.671 us; speedup vs baseline: 1.1204x; 1.0114x over previous
//
#include <hip/hip_runtime.h>

#define B_DIM 4096
#define K_TOT 2048   // IN + H
#define H_DIM 1024

typedef short bf16x8 __attribute__((ext_vector_type(8)));
typedef float f32x4 __attribute__((ext_vector_type(4)));
typedef unsigned short u16x8 __attribute__((ext_vector_type(8)));

typedef __attribute__((address_space(1))) const unsigned gas_u32;
typedef __attribute__((address_space(3))) unsigned las_u32;

static __device__ __forceinline__ unsigned short f2bf(float f) {
  union { float f; unsigned u; } v; v.f = f;
  unsigned r = v.u + 0x7FFF + ((v.u >> 16) & 1);  // RNE
  return (unsigned short)(r >> 16);
}

// ---------------- pack A and W into per-(panel, k-tile) LDS-image order ----------------
// A_pk: [by 0..15][half 0..63][v 0..1023] x 8 bf16.  half = kt*2+kh.
//   image slot v -> row r=v>>2, slot p=v&3, k-group g = p ^ ((r>>1)&3)  (XOR swizzle
//   PRE-APPLIED so gemm staging is a pure linear 16KB copy -> every global_load_lds
//   reads a contiguous 1KB span instead of 16 scattered 64B segments).
//   data = A[by*256+r][half*32 + g*8 .. +8)   (A = [x | h] concat on k)
// W_pk: same image per bx panel; packed row r encodes (ng,gate,c):
//   gate=(r>>4)&3, ng=r>>6, c=r&15, j = bx*64+ng*16+c  -> MFMA frag ni == gate,
//   so the LSTM pointwise has all 4 gates of (row,j) in one lane's accumulators.
__global__ void pack_all(const float* __restrict__ x, const float* __restrict__ hp,
                         const float* __restrict__ W0, const float* __restrict__ W1,
                         const float* __restrict__ W2, const float* __restrict__ W3,
                         const float* __restrict__ W4, const float* __restrict__ W5,
                         const float* __restrict__ W6, const float* __restrict__ W7,
                         u16x8* __restrict__ A, u16x8* __restrict__ Wc) {
  const int t = blockIdx.x * blockDim.x + threadIdx.x;
  const int NA = 1 << 20;   // 1048576 granules (16B) for A
  const float* src;
  u16x8* dst;
  if (t < NA) {
    int by = t >> 16;              // 65536 granules per 1MB panel
    int rem = t & 65535;
    int half = rem >> 10;          // 1024 granules per 16KB half-tile
    int v = rem & 1023;
    int r = v >> 2;
    int g = (v & 3) ^ ((r >> 1) & 3);
    int k = half * 32 + g * 8;     // k within [0,2048), 8-aligned (never crosses x/h seam)
    int row = by * 256 + r;
    src = (k < 1024) ? (x + row * 1024 + k) : (hp + row * 1024 + (k - 1024));
    dst = A + t;
  } else {
    int u = t - NA;
    int bx = u >> 16;
    int rem = u & 65535;
    int half = rem >> 10;
    int v = rem & 1023;
    int r = v >> 2;
    int g = (v & 3) ^ ((r >> 1) & 3);
    int k = half * 32 + g * 8;
    int gate = (r >> 4) & 3;
    int j = bx * 64 + (r >> 6) * 16 + (r & 15);
    int s = (k < 1024) ? gate : gate + 4;   // x-half -> Wx gate, h-half -> Wh gate
    const float* base =
        (s == 0) ? W0 : (s == 1) ? W1 : (s == 2) ? W2 : (s == 3) ? W3 :
        (s == 4) ? W4 : (s == 5) ? W5 : (s == 6) ? W6 : W7;
    src = base + j * 1024 + (k & 1023);
    dst = Wc + u;
  }
  float4 lo = *(const float4*)src;
  float4 hi = *(const float4*)(src + 4);
  u16x8 v8;
  v8[0] = f2bf(lo.x); v8[1] = f2bf(lo.y); v8[2] = f2bf(lo.z); v8[3] = f2bf(lo.w);
  v8[4] = f2bf(hi.x); v8[5] = f2bf(hi.y); v8[6] = f2bf(hi.z); v8[7] = f2bf(hi.w);
  *dst = v8;
}

static __device__ __forceinline__ float sigm(float x) {
  return 1.0f / (1.0f + __expf(-x));
}
static __device__ __forceinline__ float tanh_fast(float x) {
  x = fminf(fmaxf(x, -15.f), 15.f);
  float t = __expf(-2.0f * x);
  return (1.0f - t) / (1.0f + t);
}

// ------------- 256x256 8-phase counted-vmcnt GEMM + fused LSTM epilogue -------------
// BM=BN=256, BK=64. 8 waves = 2(M) x 4(N). Per-wave 128 rows x 64 cols = acc[8][4].
// LDS: 2 buffers x (A 32KB + B 32KB) = 128KB. Inputs are PRE-PACKED in LDS-image
// order (see pack_all), so each STAGE is a linear 16KB copy: 2 global_load_lds per
// thread, each a contiguous 1KB wave-span. ds_read side uses the XOR slot swizzle
// baked into the image -> conflict-free (counter-verified 0).
// Half-tile stream H=0..127 (tile kt = H>>2; H&1: A/B; (H>>1)&1: k-half). Stage runs
// 6 halves ahead; guards s_waitcnt vmcnt(8) twice per tile (never 0 in main loop).
// Tail peeled: tile 30 p3 -> vmcnt(4), tile 31 p1 -> vmcnt(0). Raw s_barrier x2 per
// phase keeps prefetch alive across barriers; setprio(1) wraps the MFMA cluster.
__global__ __launch_bounds__(512, 2) void gemm_lstm(
    const unsigned short* __restrict__ A,   // packed per-(by, half) LDS image
    const unsigned short* __restrict__ W,   // packed per-(bx, half) LDS image
    const float* __restrict__ cp,
    const float* __restrict__ bii, const float* __restrict__ bif,
    const float* __restrict__ big, const float* __restrict__ bio,
    float* __restrict__ out) {
  extern __shared__ char lds[];   // 131072 B
  const int tid = threadIdx.x;
  const int w = tid >> 6;
  const int lane = tid & 63;
  const int wm = w >> 2;          // 0..1 : M half
  const int ng = w & 3;           // 0..3 : N quarter
  const int bx = blockIdx.x;      // 64-wide j strip
  const int by = blockIdx.y;      // 256-row strip

  f32x4 acc[8][4];
#pragma unroll
  for (int i = 0; i < 8; ++i)
#pragma unroll
    for (int n = 0; n < 4; ++n)
      acc[i][n] = (f32x4){0.f, 0.f, 0.f, 0.f};

  // panel bases (1MB = 524288 elems each)
  const unsigned short* Ap = A + (size_t)by * 524288;
  const unsigned short* Wp = W + (size_t)bx * 524288;

  // ---- fragment-read constants
  const int fr = lane & 15;
  const int gg = lane >> 4;
  const int aoff = fr * 64 + ((gg ^ ((fr >> 1) & 3)) << 4);
  const int wmoff = wm << 13;     // wm*128 rows * 64B
  const int ngoff = ng << 12;     // ng*64 rows * 64B

  bf16x8 bfr[4];

#define STAGE(H)                                                                      \
  {                                                                                   \
    const int H_ = (H);                                                               \
    char* dst_ = lds + (((H_ >> 2) & 1) << 16) + ((H_ & 1) << 15) +                   \
                 (((H_ >> 1) & 1) << 14);                                             \
    const unsigned short* s_ =                                                        \
        ((H_ & 1) ? Wp : Ap) + ((((H_ >> 2) << 1) | ((H_ >> 1) & 1)) * 8192);         \
    __builtin_amdgcn_global_load_lds((gas_u32*)(s_ + (size_t)tid * 8),                \
                                     (las_u32*)(dst_ + tid * 16), 16, 0, 0);          \
    __builtin_amdgcn_global_load_lds((gas_u32*)(s_ + (size_t)(tid + 512) * 8),        \
                                     (las_u32*)(dst_ + (tid + 512) * 16), 16, 0, 0);  \
  }

#define G8 asm volatile("s_waitcnt vmcnt(8)" ::: "memory")
#define G4 asm volatile("s_waitcnt vmcnt(4)" ::: "memory")
#define G0 asm volatile("s_waitcnt vmcnt(0)" ::: "memory")
#define GN ((void)0)

#define DO_PHASE(P, KT, GUARD, DOSTAGE)                                        \
  {                                                                            \
    const char* lA_ = ldsbuf + ((P) >> 1) * 16384;                             \
    const char* lB_ = ldsbuf + 32768 + ((P) >> 1) * 16384;                     \
    bf16x8 af_[4];                                                             \
    _Pragma("unroll")                                                          \
    for (int i_ = 0; i_ < 4; ++i_)                                             \
      af_[i_] = *(const bf16x8*)(lA_ + wmoff + (((P) & 1) * 4 + i_) * 1024 + aoff); \
    if (((P) & 1) == 0) {                                                      \
      _Pragma("unroll")                                                        \
      for (int n_ = 0; n_ < 4; ++n_)                                           \
        bfr[n_] = *(const bf16x8*)(lB_ + ngoff + n_ * 1024 + aoff);            \
    }                                                                          \
    if (DOSTAGE) STAGE((KT) * 4 + (P) + 6);                                    \
    GUARD;                                                                     \
    __builtin_amdgcn_s_barrier();                                              \
    asm volatile("s_waitcnt lgkmcnt(0)" ::: "memory");                         \
    __builtin_amdgcn_sched_barrier(0);                                         \
    __builtin_amdgcn_s_setprio(1);                                             \
    _Pragma("unroll")                                                          \
    for (int i_ = 0; i_ < 4; ++i_) {                                           \
      _Pragma("unroll")                                                        \
      for (int n_ = 0; n_ < 4; ++n_)                                           \
        acc[((P) & 1) * 4 + i_][n_] = __builtin_amdgcn_mfma_f32_16x16x32_bf16( \
            af_[i_], bfr[n_], acc[((P) & 1) * 4 + i_][n_], 0, 0, 0);           \
    }                                                                          \
    __builtin_amdgcn_s_setprio(0);                                             \
    __builtin_amdgcn_s_barrier();                                              \
  }

  // ---- prologue: stage halves 0..5, wait for halves 0,1 (4 halves = 8 loads in flight)
  STAGE(0); STAGE(1); STAGE(2); STAGE(3); STAGE(4); STAGE(5);
  asm volatile("s_waitcnt vmcnt(8)" ::: "memory");
  __builtin_amdgcn_s_barrier();

  // ---- main loop: tiles 0..29, steady-state vmcnt(8)
  for (int kt = 0; kt < 30; ++kt) {
    const char* ldsbuf = lds + ((kt & 1) << 16);
    DO_PHASE(0, kt, GN, 1);
    DO_PHASE(1, kt, G8, 1);
    DO_PHASE(2, kt, GN, 1);
    DO_PHASE(3, kt, G8, 1);
  }
  // tile 30 (buffer 0): stages halves 126,127 then stream ends
  {
    const char* ldsbuf = lds;
    DO_PHASE(0, 30, GN, 1);
    DO_PHASE(1, 30, G8, 1);
    DO_PHASE(2, 30, GN, 0);
    DO_PHASE(3, 30, G4, 0);
  }
  // tile 31 (buffer 1): drain
  {
    const char* ldsbuf = lds + 65536;
    DO_PHASE(0, 31, GN, 0);
    DO_PHASE(1, 31, G0, 0);
    DO_PHASE(2, 31, GN, 0);
    DO_PHASE(3, 31, GN, 0);
  }
#undef DO_PHASE
#undef STAGE

  // ---- fused LSTM epilogue
  // C/D layout: col=lane&15, row=(lane>>4)*4+reg  [m89/m91 verified]
  // frag ni == gate; j = bx*64 + ng*16 + ccol
  const int ccol = lane & 15;
  const int crow = (lane >> 4) << 2;
  const int j = (bx << 6) + (ng << 4) + ccol;
  const float bi = bii[j];
  const float bff = bif[j];
  const float bg = big[j];
  const float bo = bio[j];
  const long BH = (long)B_DIM * H_DIM;
  const int row0 = (by << 8) + (wm << 7) + crow;
#pragma unroll
  for (int mi = 0; mi < 8; ++mi) {
#pragma unroll
    for (int reg = 0; reg < 4; ++reg) {
      const int row = row0 + mi * 16 + reg;
      const long p = (long)row * H_DIM + j;
      const float cvp = cp[p];
      const float iv = sigm(acc[mi][0][reg] + bi);
      const float fv = sigm(acc[mi][1][reg] + bff);
      const float gv = tanh_fast(acc[mi][2][reg] + bg);
      const float ov = sigm(acc[mi][3][reg] + bo);
      const float cv = fv * cvp + iv * gv;
      const float hv = ov * tanh_fast(cv);
      out[p]          = hv;
      out[BH + p]     = cv;
      out[2 * BH + p] = iv;
      out[3 * BH + p] = fv;
      out[4 * BH + p] = gv;
      out[5 * BH + p] = ov;
    }
  }
}

extern "C" void kernel_launch(void* const* d_in, const int* in_sizes, int n_in,
                              void* d_out, int out_size, void* d_ws, size_t ws_size,
                              hipStream_t stream) {
  const float* x    = (const float*)d_in[0];
  const float* h    = (const float*)d_in[1];
  const float* c    = (const float*)d_in[2];
  const float* W_ii = (const float*)d_in[3];
  const float* b_ii = (const float*)d_in[4];
  const float* W_if = (const float*)d_in[5];
  const float* b_if = (const float*)d_in[6];
  const float* W_ig = (const float*)d_in[7];
  const float* b_ig = (const float*)d_in[8];
  const float* W_io = (const float*)d_in[9];
  const float* b_io = (const float*)d_in[10];
  const float* W_hi = (const float*)d_in[11];
  const float* W_hf = (const float*)d_in[12];
  const float* W_hg = (const float*)d_in[13];
  const float* W_ho = (const float*)d_in[14];

  // workspace: A_pk bf16 16MB | W_pk bf16 16MB
  unsigned short* Abf = (unsigned short*)d_ws;
  unsigned short* Wbf = (unsigned short*)((char*)d_ws + (size_t)16 * 1024 * 1024);

  static bool s_attr = false;
  if (!s_attr) {
    hipFuncSetAttribute((const void*)gemm_lstm,
                        hipFuncAttributeMaxDynamicSharedMemorySize, 131072);
    s_attr = true;
  }

  pack_all<<<8192, 256, 0, stream>>>(x, h, W_ii, W_if, W_ig, W_io,
                                     W_hi, W_hf, W_hg, W_ho,
                                     (u16x8*)Abf, (u16x8*)Wbf);
  dim3 grid(H_DIM / 64, B_DIM / 256);   // 16 x 16 = 256 blocks = 1/CU
  gemm_lstm<<<grid, 512, 131072, stream>>>(Abf, Wbf, c, b_ii, b_if, b_ig, b_io,
                                           (float*)d_out);
}